// Round 2
// baseline (539.550 us; speedup 1.0000x reference)
//
#include <hip/hip_runtime.h>
#include <math.h>

// (B,H,N,D) = (2,16,4096,128), fp32 in/out.
static constexpr int kN   = 4096;
static constexpr int kD   = 128;
static constexpr int kBH  = 32;        // B*H channel groups
static constexpr int kD4  = 32;        // float4 per row

// Fused single-pass scan config.
static constexpr int C      = 64;      // chunks per bh
static constexpr int T      = kN / C;  // 64 timesteps per chunk
static constexpr int GROUPS = 8;       // 32-lane groups per block
static constexpr int TG     = T / GROUPS;  // 8 timesteps per group
static constexpr int REC    = kBH * C;     // 2048 records

#define AGENT __HIP_MEMORY_SCOPE_AGENT

__device__ __forceinline__ float fast_sigmoid(float x) {
    const float e = __expf(-x);
    return __builtin_amdgcn_rcpf(1.0f + e);
}

// ---------------------------------------------------------------------------
// Single-pass decoupled-lookback GLA scan.
// Block = 256 threads = 8 groups x 32 lanes; each block owns chunk (bh, c).
// ---------------------------------------------------------------------------
__global__ __launch_bounds__(256) void gla_fused(
    const float4* __restrict__ q, const float4* __restrict__ k,
    const float4* __restrict__ v, const float4* __restrict__ g,
    float4* __restrict__ out, unsigned* __restrict__ counter,
    unsigned* __restrict__ flags, float* __restrict__ payload)
{
    __shared__ float4 wscan[T][kD4];       // within-chunk inclusive scans (32 KB)
    __shared__ float4 sums[GROUPS][kD4];   // group totals, reused for lookback (4 KB)
    __shared__ unsigned s_ticket;

    const int tid = threadIdx.x;
    const int l   = tid & 31;              // d-quad lane
    const int grp = tid >> 5;              // group 0..7

    // Ticket: acquisition order == execution-start order -> lookback can never
    // wait on a block that hasn't started (deadlock-free regardless of
    // dispatch order; only ~1024 of 2048 blocks are co-resident).
    if (tid == 0) s_ticket = atomicAdd(counter, 1u);
    __syncthreads();
    const unsigned ticket = s_ticket;
    const int c   = (int)(ticket >> 5);    // chunk-major: all bh progress together
    const int bh  = (int)(ticket & 31);
    const int rec = bh * C + c;

    // ---- Phase A: load, gate, within-group inclusive scan (held in LDS) ----
    const size_t base = ((size_t)bh * kN + (size_t)c * T + grp * TG) * kD4 + l;
    float4 acc = make_float4(0.f, 0.f, 0.f, 0.f);
#pragma unroll
    for (int t = 0; t < TG; ++t) {
        const size_t idx = base + (size_t)t * kD4;
        const float4 q4 = q[idx];
        const float4 k4 = k[idx];
        const float4 g4 = g[idx];
        const float4 v4 = v[idx];
        acc.x += v4.x * fast_sigmoid(q4.x * k4.x + g4.x);
        acc.y += v4.y * fast_sigmoid(q4.y * k4.y + g4.y);
        acc.z += v4.z * fast_sigmoid(q4.z * k4.z + g4.z);
        acc.w += v4.w * fast_sigmoid(q4.w * k4.w + g4.w);
        wscan[grp * TG + t][l] = acc;
    }
    sums[grp][l] = acc;
    __syncthreads();

    // Exclusive prefix of group totals for this thread's group.
    float4 gpre = make_float4(0.f, 0.f, 0.f, 0.f);
    for (int g2 = 0; g2 < grp; ++g2) {
        const float4 s = sums[g2][l];
        gpre.x += s.x; gpre.y += s.y; gpre.z += s.z; gpre.w += s.w;
    }

    // ---- Publish this chunk's total (partial-only; slot never overwritten) ----
    if (grp == 0) {
        float4 bt = make_float4(0.f, 0.f, 0.f, 0.f);
#pragma unroll
        for (int g2 = 0; g2 < GROUPS; ++g2) {
            const float4 s = sums[g2][l];
            bt.x += s.x; bt.y += s.y; bt.z += s.z; bt.w += s.w;
        }
        float* p = payload + (size_t)rec * kD + l * 4;
        __hip_atomic_store(p + 0, bt.x, __ATOMIC_RELAXED, AGENT);
        __hip_atomic_store(p + 1, bt.y, __ATOMIC_RELAXED, AGENT);
        __hip_atomic_store(p + 2, bt.z, __ATOMIC_RELAXED, AGENT);
        __hip_atomic_store(p + 3, bt.w, __ATOMIC_RELAXED, AGENT);
        __threadfence();
        if (tid == 0)
            __hip_atomic_store(&flags[rec], 1u, __ATOMIC_RELEASE, AGENT);
    }
    __syncthreads();   // everyone done reading sums[] -> safe to reuse for lookback

    // ---- Parallel lookback: sum partials of all predecessor chunks ----
    float4 lb = make_float4(0.f, 0.f, 0.f, 0.f);
    for (int idx = c - 1 - grp; idx >= 0; idx -= GROUPS) {
        const int r2 = bh * C + idx;
        if (l == 0) {
            while (__hip_atomic_load(&flags[r2], __ATOMIC_ACQUIRE, AGENT) == 0u)
                __builtin_amdgcn_s_sleep(2);
        }
        const float* p = payload + (size_t)r2 * kD + l * 4;
        lb.x += __hip_atomic_load(p + 0, __ATOMIC_RELAXED, AGENT);
        lb.y += __hip_atomic_load(p + 1, __ATOMIC_RELAXED, AGENT);
        lb.z += __hip_atomic_load(p + 2, __ATOMIC_RELAXED, AGENT);
        lb.w += __hip_atomic_load(p + 3, __ATOMIC_RELAXED, AGENT);
    }
    sums[grp][l] = lb;
    __syncthreads();

    float4 bpre = make_float4(0.f, 0.f, 0.f, 0.f);
#pragma unroll
    for (int g2 = 0; g2 < GROUPS; ++g2) {
        const float4 s = sums[g2][l];
        bpre.x += s.x; bpre.y += s.y; bpre.z += s.z; bpre.w += s.w;
    }

    // ---- Phase C: add prefixes, single write of out ----
    const float4 addv = make_float4(bpre.x + gpre.x, bpre.y + gpre.y,
                                    bpre.z + gpre.z, bpre.w + gpre.w);
#pragma unroll
    for (int t = 0; t < TG; ++t) {
        const size_t idx = base + (size_t)t * kD4;
        const float4 w = wscan[grp * TG + t][l];
        out[idx] = make_float4(w.x + addv.x, w.y + addv.y,
                               w.z + addv.z, w.w + addv.w);
    }
}

// ---------------------------------------------------------------------------
// Fallback 3-pass path (known-good from round 1) in case ws is tiny.
// ---------------------------------------------------------------------------
template <int CC>
__global__ __launch_bounds__(256) void gla_pass1(
    const float4* __restrict__ q, const float4* __restrict__ k,
    const float4* __restrict__ v, const float4* __restrict__ g,
    float4* __restrict__ out, float4* __restrict__ sums)
{
    constexpr int TT = kN / CC;
    const int gtid = blockIdx.x * 256 + threadIdx.x;
    const int lane = gtid & (kD4 - 1);
    const int task = gtid >> 5;
    const int bh   = task / CC;
    const int c    = task & (CC - 1);
    size_t base = ((size_t)bh * kN + (size_t)c * TT) * kD4 + lane;
    float4 acc = make_float4(0.f, 0.f, 0.f, 0.f);
#pragma unroll 4
    for (int t = 0; t < TT; ++t) {
        const size_t idx = base + (size_t)t * kD4;
        const float4 q4 = q[idx], k4 = k[idx], g4 = g[idx], v4 = v[idx];
        acc.x += v4.x * fast_sigmoid(q4.x * k4.x + g4.x);
        acc.y += v4.y * fast_sigmoid(q4.y * k4.y + g4.y);
        acc.z += v4.z * fast_sigmoid(q4.z * k4.z + g4.z);
        acc.w += v4.w * fast_sigmoid(q4.w * k4.w + g4.w);
        out[idx] = acc;
    }
    sums[(size_t)task * kD4 + lane] = acc;
}

template <int CC>
__global__ void gla_pass2(float* __restrict__ sums)
{
    const int bh = blockIdx.x;
    const int d  = threadIdx.x;
    size_t base = (size_t)bh * CC * kD + d;
    float run = 0.f;
#pragma unroll
    for (int c2 = 0; c2 < CC; ++c2) {
        const size_t i = base + (size_t)c2 * kD;
        const float t = sums[i];
        sums[i] = run;
        run += t;
    }
}

template <int CC>
__global__ __launch_bounds__(256) void gla_pass3(
    float4* __restrict__ out, const float4* __restrict__ sums)
{
    constexpr int TT = kN / CC;
    const int gtid = blockIdx.x * 256 + threadIdx.x;
    const int lane = gtid & (kD4 - 1);
    const int nt   = gtid >> 5;
    const int bh   = nt / kN;
    const int t    = nt & (kN - 1);
    const int c    = t / TT;
    const float4 add = sums[((size_t)bh * CC + c) * kD4 + lane];
    float4 o = out[gtid];
    o.x += add.x; o.y += add.y; o.z += add.z; o.w += add.w;
    out[gtid] = o;
}

// ---------------------------------------------------------------------------
extern "C" void kernel_launch(void* const* d_in, const int* in_sizes, int n_in,
                              void* d_out, int out_size, void* d_ws,
                              size_t ws_size, hipStream_t stream)
{
    const float4* q = (const float4*)d_in[0];
    const float4* k = (const float4*)d_in[1];
    const float4* v = (const float4*)d_in[2];
    const float4* g = (const float4*)d_in[3];
    float4* out = (float4*)d_out;

    // ws layout: [0,1KB) counter | [1KB,9KB) flags | [16KB, 16KB+1MiB) payload
    constexpr size_t kPayloadOff = 16384;
    constexpr size_t kNeed = kPayloadOff + (size_t)REC * kD * sizeof(float);

    if (ws_size >= kNeed) {
        unsigned* counter = (unsigned*)d_ws;
        unsigned* flags   = (unsigned*)((char*)d_ws + 1024);
        float*    payload = (float*)((char*)d_ws + kPayloadOff);
        // Reset counter + flags every call (captured in the graph).
        hipMemsetAsync(d_ws, 0, kPayloadOff, stream);
        gla_fused<<<REC, 256, 0, stream>>>(q, k, v, g, out, counter, flags,
                                           payload);
    } else {
        // Known-good 3-pass fallback (needs 512 KiB).
        constexpr int CC = 32;
        const int threads1 = kBH * CC * 32;
        gla_pass1<CC><<<threads1 / 256, 256, 0, stream>>>(q, k, v, g, out,
                                                          (float4*)d_ws);
        gla_pass2<CC><<<kBH, kD, 0, stream>>>((float*)d_ws);
        const int threads3 = kBH * kN * kD4;
        gla_pass3<CC><<<threads3 / 256, 256, 0, stream>>>(out,
                                                          (const float4*)d_ws);
    }
}

// Round 5
// 81.549 us; speedup vs baseline: 6.6163x; 6.6163x over previous
//
#include <hip/hip_runtime.h>
#include <math.h>

// (B,H,N,D) = (2,16,4096,128), fp32 in/out.
static constexpr int kN   = 4096;
static constexpr int kD   = 128;
static constexpr int kBH  = 32;        // B*H channel groups
static constexpr int kD4  = 32;        // float4 (d-quads) per row

typedef float  v4f __attribute__((ext_vector_type(4)));

__device__ __forceinline__ float fast_sigmoid(float x) {
    return __builtin_amdgcn_rcpf(1.0f + __expf(-x));
}

// round-to-nearest-even fp32 -> bf16
__device__ __forceinline__ unsigned short f2b(float x) {
    union { float f; unsigned u; } cv; cv.f = x;
    unsigned u = cv.u;
    u += 0x7fffu + ((u >> 16) & 1u);
    return (unsigned short)(u >> 16);
}
__device__ __forceinline__ float b2f(unsigned short b) {
    union { unsigned u; float f; } cv; cv.u = ((unsigned)b) << 16;
    return cv.f;
}

// ===========================================================================
// Primary path: C=512 chunks (T=8), bf16 within-chunk scan staged in ws.
// ===========================================================================
static constexpr int C1 = 512;
static constexpr int T1 = kN / C1;                  // 8
static constexpr int TASKS1 = kBH * C1;             // 16384 (32-lane tasks)

// Pass 1: gated within-chunk inclusive scan -> bf16 ws; chunk totals -> sums.
__global__ __launch_bounds__(256) void gla1_scan(
    const float4* __restrict__ q, const float4* __restrict__ k,
    const float4* __restrict__ v, const float4* __restrict__ g,
    ushort4* __restrict__ wscan, float4* __restrict__ sums)
{
    const int gtid = blockIdx.x * 256 + threadIdx.x;
    const int lane = gtid & (kD4 - 1);
    const int task = gtid >> 5;            // bh*C1 + c
    const int bh   = task >> 9;            // /512
    const int c    = task & (C1 - 1);

    const size_t base = ((size_t)bh * kN + (size_t)c * T1) * kD4 + lane;
    float4 acc = make_float4(0.f, 0.f, 0.f, 0.f);
#pragma unroll
    for (int t = 0; t < T1; ++t) {
        const size_t idx = base + (size_t)t * kD4;
        const float4 q4 = q[idx];
        const float4 k4 = k[idx];
        const float4 g4 = g[idx];
        const float4 v4 = v[idx];
        acc.x += v4.x * fast_sigmoid(q4.x * k4.x + g4.x);
        acc.y += v4.y * fast_sigmoid(q4.y * k4.y + g4.y);
        acc.z += v4.z * fast_sigmoid(q4.z * k4.z + g4.z);
        acc.w += v4.w * fast_sigmoid(q4.w * k4.w + g4.w);
        ushort4 p;
        p.x = f2b(acc.x); p.y = f2b(acc.y); p.z = f2b(acc.z); p.w = f2b(acc.w);
        wscan[idx] = p;
    }
    sums[(size_t)task * kD4 + lane] = acc;   // [bh][c][dq]
}

// Pass 2: in-place exclusive scan over C1 chunk totals per (bh,d) channel.
// 32 blocks x 128 threads; loads/stores coalesced (thread = d).
__global__ void gla1_chunkscan(float* __restrict__ sums)
{
    const int bh = blockIdx.x;
    const int d  = threadIdx.x;             // 0..127
    const size_t base = (size_t)bh * C1 * kD + d;
    float run = 0.f;
    for (int c0 = 0; c0 < C1; c0 += 8) {
        float tv[8];
#pragma unroll
        for (int j = 0; j < 8; ++j)
            tv[j] = sums[base + (size_t)(c0 + j) * kD];
#pragma unroll
        for (int j = 0; j < 8; ++j) {
            const float t = tv[j];
            sums[base + (size_t)(c0 + j) * kD] = run;
            run += t;
        }
    }
}

// Pass 3: out = bf16(wscan) + chunk_prefix. Single non-temporal write of out.
__global__ __launch_bounds__(256) void gla1_emit(
    const ushort4* __restrict__ wscan, const float4* __restrict__ sums,
    float4* __restrict__ out)
{
    const int gtid = blockIdx.x * 256 + threadIdx.x;
    const int lane = gtid & (kD4 - 1);
    const int task = gtid >> 5;
    const int bh   = task >> 9;
    const int c    = task & (C1 - 1);

    const float4 pre = sums[(size_t)task * kD4 + lane];
    const size_t base = ((size_t)bh * kN + (size_t)c * T1) * kD4 + lane;
#pragma unroll
    for (int t = 0; t < T1; ++t) {
        const size_t idx = base + (size_t)t * kD4;
        const ushort4 p = wscan[idx];
        v4f o;
        o.x = b2f(p.x) + pre.x;
        o.y = b2f(p.y) + pre.y;
        o.z = b2f(p.z) + pre.z;
        o.w = b2f(p.w) + pre.w;
        __builtin_nontemporal_store(o, (v4f*)&out[idx]);
    }
}

// ===========================================================================
// Fallback path (proven round-1 code): C=128 or C=32, fp32 scan in out.
// ===========================================================================
template <int CC>
__global__ __launch_bounds__(256) void gla_pass1(
    const float4* __restrict__ q, const float4* __restrict__ k,
    const float4* __restrict__ v, const float4* __restrict__ g,
    float4* __restrict__ out, float4* __restrict__ sums)
{
    constexpr int TT = kN / CC;
    const int gtid = blockIdx.x * 256 + threadIdx.x;
    const int lane = gtid & (kD4 - 1);
    const int task = gtid >> 5;
    const int bh   = task / CC;
    const int c    = task & (CC - 1);
    size_t base = ((size_t)bh * kN + (size_t)c * TT) * kD4 + lane;
    float4 acc = make_float4(0.f, 0.f, 0.f, 0.f);
#pragma unroll 4
    for (int t = 0; t < TT; ++t) {
        const size_t idx = base + (size_t)t * kD4;
        const float4 q4 = q[idx], k4 = k[idx], g4 = g[idx], v4 = v[idx];
        acc.x += v4.x * fast_sigmoid(q4.x * k4.x + g4.x);
        acc.y += v4.y * fast_sigmoid(q4.y * k4.y + g4.y);
        acc.z += v4.z * fast_sigmoid(q4.z * k4.z + g4.z);
        acc.w += v4.w * fast_sigmoid(q4.w * k4.w + g4.w);
        out[idx] = acc;
    }
    sums[(size_t)task * kD4 + lane] = acc;
}

template <int CC>
__global__ void gla_pass2(float* __restrict__ sums)
{
    const int bh = blockIdx.x;
    const int d  = threadIdx.x;
    size_t base = (size_t)bh * CC * kD + d;
    float run = 0.f;
#pragma unroll
    for (int c2 = 0; c2 < CC; ++c2) {
        const size_t i = base + (size_t)c2 * kD;
        const float t = sums[i];
        sums[i] = run;
        run += t;
    }
}

template <int CC>
__global__ __launch_bounds__(256) void gla_pass3(
    float4* __restrict__ out, const float4* __restrict__ sums)
{
    constexpr int TT = kN / CC;
    const int gtid = blockIdx.x * 256 + threadIdx.x;
    const int lane = gtid & (kD4 - 1);
    const int nt   = gtid >> 5;
    const int bh   = nt / kN;
    const int t    = nt & (kN - 1);
    const int c    = t / TT;
    const float4 add = sums[((size_t)bh * CC + c) * kD4 + lane];
    float4 o = out[gtid];
    o.x += add.x; o.y += add.y; o.z += add.z; o.w += add.w;
    out[gtid] = o;
}

// ===========================================================================
extern "C" void kernel_launch(void* const* d_in, const int* in_sizes, int n_in,
                              void* d_out, int out_size, void* d_ws,
                              size_t ws_size, hipStream_t stream)
{
    const float4* q = (const float4*)d_in[0];
    const float4* k = (const float4*)d_in[1];
    const float4* v = (const float4*)d_in[2];
    const float4* g = (const float4*)d_in[3];
    float4* out = (float4*)d_out;

    // Primary ws layout: [0, 32MiB) bf16 wscan | [32MiB, 40MiB) fp32 sums
    constexpr size_t kWscanBytes = (size_t)kBH * kN * kD4 * sizeof(ushort4); // 33.55 MB
    constexpr size_t kSumsBytes  = (size_t)TASKS1 * kD4 * sizeof(float4);    //  8.39 MB
    constexpr size_t kNeed1 = kWscanBytes + kSumsBytes;

    if (ws_size >= kNeed1) {
        ushort4* wscan = (ushort4*)d_ws;
        float4*  sums  = (float4*)((char*)d_ws + kWscanBytes);
        const int blocks = TASKS1 * 32 / 256;   // 2048
        gla1_scan<<<blocks, 256, 0, stream>>>(q, k, v, g, wscan, sums);
        gla1_chunkscan<<<kBH, kD, 0, stream>>>((float*)sums);
        gla1_emit<<<blocks, 256, 0, stream>>>(wscan, sums, out);
    } else if (ws_size >= (size_t)kBH * 128 * kD * sizeof(float)) {
        constexpr int CC = 128;
        const int threads1 = kBH * CC * 32;
        gla_pass1<CC><<<threads1 / 256, 256, 0, stream>>>(q, k, v, g, out,
                                                          (float4*)d_ws);
        gla_pass2<CC><<<kBH, kD, 0, stream>>>((float*)d_ws);
        const int threads3 = kBH * kN * kD4;
        gla_pass3<CC><<<threads3 / 256, 256, 0, stream>>>(out,
                                                          (const float4*)d_ws);
    } else {
        constexpr int CC = 32;
        const int threads1 = kBH * CC * 32;
        gla_pass1<CC><<<threads1 / 256, 256, 0, stream>>>(q, k, v, g, out,
                                                          (float4*)d_ws);
        gla_pass2<CC><<<kBH, kD, 0, stream>>>((float*)d_ws);
        const int threads3 = kBH * kN * kD4;
        gla_pass3<CC><<<threads3 / 256, 256, 0, stream>>>(out,
                                                          (const float4*)d_ws);
    }
}